// Round 5
// baseline (189.225 us; speedup 1.0000x reference)
//
#include <hip/hip_runtime.h>

#define B_SZ  128
#define MCHK  288
#define NVAR  576
#define KINFO 288
#define NITER 5
#define ECAP  3712         // compact edge capacity (mean 3318, sd ~57)
#define CAP2  32           // padded slots/row for bucket scatter (P(row>32) ~ 1e-14)
#define TPB   1024
#define NQ4   (MCHK * NVAR / 4)   // 41472 float4 per batch element
#define Q4ROW (NVAR / 4)          // 144 float4 per row

// ---------------------------------------------------------------------------
// One block per batch element, no cross-block coupling.
// Extraction v2 (the round-4 VALU hog, ~33us, replaced):
//   A: thread-per-element coalesced float4 stream; nonzeros bucket-scatter
//      (col as u16) into padded per-row slots via low-contention LDS atomics.
//   B: 2-barrier shfl scan of row counts -> compact offsets.
//   C: slot-parallel compaction + L2-hot w_cv gather -> compact edge arrays.
// BP loop (3 barriers/iter): edge-parallel tanh -> row-parallel 4-batched
//   product -> edge-parallel message + gated update + LDS scatter into a
//   fresh S snapshot (normalization fully deferred to the epilogue).
// ---------------------------------------------------------------------------
__global__ __launch_bounds__(TPB) void decode(
    const float* __restrict__ inp,   const float* __restrict__ H,
    const float* __restrict__ sigma2,const float* __restrict__ ipond,
    const float* __restrict__ opond, const float* __restrict__ skipp,
    const float* __restrict__ wcv,   const float* __restrict__ gatel,
    float* __restrict__ out)
{
    __shared__ float Mld[ECAP];            // per-edge message
    __shared__ float tld[ECAP];            // per-edge tanh
    __shared__ float wld[ECAP];            // per-edge weight
    __shared__ unsigned int ev[ECAP];      // (row<<16)|var
    __shared__ float Sb[NITER + 1][NVAR];  // S after iter t lives in Sb[t+1]
    __shared__ float xln[NVAR];            // normalized LLRs
    __shared__ float Prow[MCHK];
    __shared__ int   rcnt[MCHK], roff[MCHK];
    __shared__ unsigned short vpad[MCHK * CAP2];   // padded bucket scatter
    __shared__ float red[NITER * 16];
    __shared__ float scalv[NITER];
    __shared__ int   wtot[8], wbase[8];

    const int b    = blockIdx.x;
    const int tid  = threadIdx.x;
    const int wid  = tid >> 6;
    const int lane = tid & 63;

    const float sig  = sigma2[b];
    const float gate = 1.0f / (1.0f + __expf(-gatel[0]));
    const float gbar = 1.0f - gate;

    float ipl[NITER], opl[NITER];
    #pragma unroll
    for (int t = 0; t < NITER; ++t) { ipl[t] = ipond[t]; opl[t] = opond[t]; }

    // ---- setup: LLRs + mean|llr|; zero rcnt and S snapshots ----
    float l = 0.0f, al = 0.0f, xv = 0.0f;
    if (tid < NVAR) { l = -4.0f * inp[(size_t)b * NVAR + tid] / sig; al = fabsf(l); }
    #pragma unroll
    for (int o = 32; o; o >>= 1) al += __shfl_down(al, o, 64);
    if (lane == 0) red[wid] = al;
    if (tid < MCHK) rcnt[tid] = 0;
    for (int i = tid; i < (NITER + 1) * NVAR; i += TPB) ((float*)Sb)[i] = 0.0f;
    __syncthreads();
    if (wid == 0) {
        float s = (lane < 16) ? red[lane] : 0.0f;
        s += __shfl_down(s, 8, 64); s += __shfl_down(s, 4, 64);
        s += __shfl_down(s, 2, 64); s += __shfl_down(s, 1, 64);
        if (lane == 0) scalv[0] = (float)NVAR / s;
    }
    __syncthreads();
    if (tid < NVAR) { xv = l * scalv[0]; xln[tid] = xv; }

    // ---- Phase A: coalesced element stream, bucket scatter of nonzeros ----
    {
        const float4* H4 = (const float4*)(H + (size_t)b * MCHK * NVAR);
        for (int k = 0; k < (NQ4 + TPB - 1) / TPB; ++k) {
            int q = tid + k * TPB;
            if (q >= NQ4) break;
            float4 hv = H4[q];
            if (hv.x != 0.f || hv.y != 0.f || hv.z != 0.f || hv.w != 0.f) {
                int r  = q / Q4ROW;                 // float4 never crosses a row
                int c0 = (q - r * Q4ROW) * 4;
                unsigned short* vp = vpad + r * CAP2;
                if (hv.x != 0.f) { int j = atomicAdd(&rcnt[r], 1); if (j < CAP2) vp[j] = (unsigned short)(c0);     }
                if (hv.y != 0.f) { int j = atomicAdd(&rcnt[r], 1); if (j < CAP2) vp[j] = (unsigned short)(c0 + 1); }
                if (hv.z != 0.f) { int j = atomicAdd(&rcnt[r], 1); if (j < CAP2) vp[j] = (unsigned short)(c0 + 2); }
                if (hv.w != 0.f) { int j = atomicAdd(&rcnt[r], 1); if (j < CAP2) vp[j] = (unsigned short)(c0 + 3); }
            }
        }
    }
    __syncthreads();

    // ---- Phase B: scan row counts (2 barriers, shfl-based) ----
    int cc = 0, incl = 0;
    if (tid < 512) {                       // waves 0..7 (288 real rows + zeros)
        cc = (tid < MCHK) ? rcnt[tid] : 0;
        if (cc > CAP2) cc = CAP2;
        incl = cc;
        #pragma unroll
        for (int o = 1; o < 64; o <<= 1) {
            int n = __shfl_up(incl, o, 64);
            if (lane >= o) incl += n;
        }
        if (lane == 63) wtot[wid] = incl;
    }
    __syncthreads();
    if (tid == 0) {
        int s = 0;
        #pragma unroll
        for (int i = 0; i < 8; ++i) { wbase[i] = s; s += wtot[i]; }
    }
    __syncthreads();
    if (tid < MCHK) {
        int o = incl + wbase[wid] - cc;    // exclusive offset
        int ce = cc;
        if (o >= ECAP)           { o = 0; ce = 0; }
        else if (o + ce > ECAP)  { ce = ECAP - o; }
        roff[tid] = o; rcnt[tid] = ce;
    }
    const int Etot = wbase[7] + wtot[7];
    const int E    = (Etot > ECAP) ? ECAP : Etot;
    __syncthreads();

    // ---- Phase C: compaction + w_cv gather (L2-hot, scattered) ----
    for (int s = tid; s < MCHK * CAP2; s += TPB) {
        int r = s >> 5, j = s & (CAP2 - 1);
        if (j < rcnt[r]) {
            int e   = roff[r] + j;
            int col = vpad[s];
            ev[e]  = ((unsigned)r << 16) | (unsigned)col;
            wld[e] = wcv[r * NVAR + col];
            Mld[e] = 0.0f;
        }
    }
    __syncthreads();

    // ---- BP iterations: 3 barriers each, no reductions inside ----
    for (int t = 0; t < NITER; ++t) {
        const float pt = ipl[t];
        const float* St = Sb[t];
        float*       Sn = Sb[t + 1];

        // P1: per-edge tanh(0.5*clip(pt*xln[v] + S[v] - M[e]))
        for (int e = tid; e < E; e += TPB) {
            int v   = (int)(ev[e] & 0xFFFFu);
            float V = fmaf(pt, xln[v], St[v]) - Mld[e];
            V = fminf(15.0f, fmaxf(-15.0f, V));
            float ex = __expf(V);
            float te = (ex - 1.0f) * __builtin_amdgcn_rcpf(ex + 1.0f);
            float x  = 0.5f * V, x2 = x * x;
            float tp = x * fmaf(x2, fmaf(x2, fmaf(x2, -0.05396825f, 0.13333333f),
                                         -0.33333333f), 1.0f);
            tld[e] = (fabsf(V) < 0.5f) ? tp : te;
        }
        __syncthreads();

        // P2: row products, 4 independent partials (batches LDS latency)
        if (tid < MCHK) {
            int o = roff[tid], oe = o + rcnt[tid];
            float p0 = 1.0f, p1 = 1.0f, p2 = 1.0f, p3 = 1.0f;
            int j = o;
            for (; j + 4 <= oe; j += 4) {
                float t0 = tld[j], t1 = tld[j + 1], t2 = tld[j + 2], t3 = tld[j + 3];
                p0 *= t0; p1 *= t1; p2 *= t2; p3 *= t3;
            }
            for (; j < oe; ++j) p0 *= tld[j];
            Prow[tid] = (p0 * p1) * (p2 * p3);
        }
        __syncthreads();

        // P3: per-edge c2v message + gated update + scatter into Sn
        for (int e = tid; e < E; e += TPB) {
            unsigned pk = ev[e];
            int v = (int)(pk & 0xFFFFu);
            int r = (int)(pk >> 16);
            float tj = tld[e];
            float ts = (fabsf(tj) < 1e-7f) ? ((tj >= 0.0f) ? 1e-7f : -1e-7f) : tj;
            float rr = Prow[r] * __builtin_amdgcn_rcpf(ts);
            rr = fminf(1.0f - 1e-6f, fmaxf(-1.0f + 1e-6f, rr));
            float Mn = __logf((1.0f + rr) * __builtin_amdgcn_rcpf(1.0f - rr)) * wld[e];
            float Mo = fmaf(gate, Mn, gbar * Mld[e]);
            Mld[e] = Mo;
            atomicAdd(&Sn[v], Mo);
        }
        __syncthreads();
    }

    // ---- epilogue: all 5 normalizations at once, pooling, output ----
    float ap[NITER] = {0, 0, 0, 0, 0};
    if (tid < NVAR) {
        #pragma unroll
        for (int t = 0; t < NITER; ++t)
            ap[t] = fabsf(fmaf(ipl[t], xv, Sb[t + 1][tid]));
    }
    #pragma unroll
    for (int o = 32; o; o >>= 1) {
        #pragma unroll
        for (int t = 0; t < NITER; ++t) ap[t] += __shfl_down(ap[t], o, 64);
    }
    if (lane == 0) {
        #pragma unroll
        for (int t = 0; t < NITER; ++t) red[t * 16 + wid] = ap[t];
    }
    __syncthreads();
    if (wid == 0) {
        #pragma unroll
        for (int t = 0; t < NITER; ++t) {
            float s = (lane < 16) ? red[t * 16 + lane] : 0.0f;
            s += __shfl_down(s, 8, 64); s += __shfl_down(s, 4, 64);
            s += __shfl_down(s, 2, 64); s += __shfl_down(s, 1, 64);
            if (lane == 0) scalv[t] = (float)NVAR / s;
        }
    }
    __syncthreads();
    if (tid < KINFO) {
        float acc = 0.0f;
        #pragma unroll
        for (int t = 0; t < NITER; ++t)
            acc += opl[t] * fmaf(ipl[t], xv, Sb[t + 1][tid]) * scalv[t];
        float o = acc * (1.0f / NITER) + skipp[0] * xv;
        out[(size_t)b * KINFO + tid] = 1.0f / (1.0f + __expf(o));
    }
}

extern "C" void kernel_launch(void* const* d_in, const int* in_sizes, int n_in,
                              void* d_out, int out_size, void* d_ws, size_t ws_size,
                              hipStream_t stream) {
    const float* inp    = (const float*)d_in[0];
    const float* H      = (const float*)d_in[1];
    const float* sigma2 = (const float*)d_in[2];
    const float* ipond  = (const float*)d_in[3];
    const float* opond  = (const float*)d_in[4];
    const float* skipp  = (const float*)d_in[5];
    const float* wcv    = (const float*)d_in[6];
    const float* gatel  = (const float*)d_in[7];
    float* out = (float*)d_out;

    decode<<<B_SZ, TPB, 0, stream>>>(inp, H, sigma2, ipond, opond, skipp,
                                     wcv, gatel, out);
}